// Round 6
// baseline (29.645 us; speedup 1.0000x reference)
//
#include <hip/hip_runtime.h>

#define N_PTS 512
#define DIM 128
#define F4_PER_ROW 32          // 128 floats / 4
#define TILE_ROWS 64
#define TILE_F4 (TILE_ROWS * F4_PER_ROW)   // 2048 float4 per tile
#define LDS_STRIDE 33          // padded float4 row stride
#define NBLOCKS 256
#define TLMARGIN 1.0f

// Single worker kernel: 256 blocks x 512 threads, block b owns anchors {2b, 2b+1}.
// Phase 1: stage input in 8 LDS tiles of 64 rows; each 8-lane group computes
//          dot(a0,row), dot(a1,row), and ||row||^2 in one pass (no transpose,
//          no separate sq kernel).
// Phase 2: semi-hard mining per row (identical to the verified round-5 code).
// Phase 3: last-block-done reduction of rl[512] -> scalar out.
__global__ __launch_bounds__(512)
void triplet_all(const float* __restrict__ inp,
                 const int* __restrict__ tgt,
                 float2* __restrict__ rl,
                 unsigned int* __restrict__ ticket,
                 float* __restrict__ out) {
  const int i0 = blockIdx.x * 2;
  const int tid = threadIdx.x;
  const int lane = tid & 63;
  const int wave = tid >> 6;
  const int jj = tid >> 3;     // row within tile (0..63)
  const int s = tid & 7;       // 16-dim slice (0..7)

  __shared__ float4 tile[TILE_ROWS * LDS_STRIDE];  // 33.8 KB
  __shared__ float d[2][N_PTS];
  __shared__ int lab[N_PTS];
  __shared__ float red[16];
  __shared__ unsigned long long pmask[8];
  __shared__ int plist[N_PTS];
  __shared__ int lastFlag;

  lab[tid] = tgt[tid];

  const float4* inp4 = reinterpret_cast<const float4*>(inp);

  // ---- anchor s-slice fragments in registers + squared norms
  float4 a0f[4], a1f[4];
  float sq0 = 0.f, sq1 = 0.f;
#pragma unroll
  for (int q = 0; q < 4; ++q) {
    a0f[q] = inp4[i0 * F4_PER_ROW + s * 4 + q];
    a1f[q] = inp4[(i0 + 1) * F4_PER_ROW + s * 4 + q];
    sq0 += a0f[q].x * a0f[q].x + a0f[q].y * a0f[q].y + a0f[q].z * a0f[q].z + a0f[q].w * a0f[q].w;
    sq1 += a1f[q].x * a1f[q].x + a1f[q].y * a1f[q].y + a1f[q].z * a1f[q].z + a1f[q].w * a1f[q].w;
  }
#pragma unroll
  for (int off = 1; off <= 4; off <<= 1) {
    sq0 += __shfl_xor(sq0, off);
    sq1 += __shfl_xor(sq1, off);
  }
  const float sqi0 = sq0, sqi1 = sq1;

  // ---- pdist rows for both anchors, tiled through LDS
  for (int tt = 0; tt < N_PTS / TILE_ROWS; ++tt) {
#pragma unroll
    for (int q = 0; q < 4; ++q) {
      const int idx = q * 512 + tid;            // 0..2047
      const int row = idx >> 5, col = idx & 31;
      tile[row * LDS_STRIDE + col] = inp4[tt * TILE_F4 + idx];  // coalesced
    }
    __syncthreads();

    float dot0 = 0.f, dot1 = 0.f, sqj = 0.f;
#pragma unroll
    for (int q = 0; q < 4; ++q) {
      const float4 bv = tile[jj * LDS_STRIDE + s * 4 + q];
      dot0 += a0f[q].x * bv.x + a0f[q].y * bv.y + a0f[q].z * bv.z + a0f[q].w * bv.w;
      dot1 += a1f[q].x * bv.x + a1f[q].y * bv.y + a1f[q].z * bv.z + a1f[q].w * bv.w;
      sqj += bv.x * bv.x + bv.y * bv.y + bv.z * bv.z + bv.w * bv.w;
    }
#pragma unroll
    for (int off = 1; off <= 4; off <<= 1) {
      dot0 += __shfl_xor(dot0, off);
      dot1 += __shfl_xor(dot1, off);
      sqj += __shfl_xor(sqj, off);
    }
    if (s == 0) {
      const int j = tt * TILE_ROWS + jj;
      float pd0 = fmaxf(sqi0 + sqj - 2.0f * dot0, 0.0f);
      float pd1 = fmaxf(sqi1 + sqj - 2.0f * dot1, 0.0f);
      if (j == i0) pd0 = 0.0f;
      if (j == i0 + 1) pd1 = 0.0f;
      d[0][j] = pd0;
      d[1][j] = pd1;
    }
    __syncthreads();
  }

  // ---- per-row semi-hard mining (verified round-5 code)
  for (int r = 0; r < 2; ++r) {
    const int i = i0 + r;
    const int li = lab[i];

    float nm = (lab[tid] != li) ? d[r][tid] : 0.0f;
#pragma unroll
    for (int off = 32; off; off >>= 1) nm = fmaxf(nm, __shfl_xor(nm, off));
    if (lane == 0) red[wave] = nm;

    const bool isPos = (lab[tid] == li) && (tid != i);
    const unsigned long long m = __ballot(isPos);
    if (lane == 0) pmask[wave] = m;
    __syncthreads();

    float neg_inside = red[0];
#pragma unroll
    for (int w = 1; w < 8; ++w) neg_inside = fmaxf(neg_inside, red[w]);

    int P = 0, rank = 0;
#pragma unroll
    for (int w = 0; w < 8; ++w) {
      const int c = __popcll(pmask[w]);
      if (w < wave) rank += c;
      P += c;
    }
    rank += __popcll(pmask[wave] & ((1ull << lane) - 1ull));
    if (isPos) plist[rank] = tid;
    __syncthreads();

    float losssum = 0.0f;
    float pcount = 0.0f;
    for (int p = wave; p < P; p += 8) {
      const int j = plist[p];
      const float dj = d[r][j];
      float mn = __builtin_inff();
#pragma unroll
      for (int kk = 0; kk < N_PTS / 64; ++kk) {
        const int k = lane + (kk << 6);
        const float dk = d[r][k];
        if (lab[k] != li && dk > dj) mn = fminf(mn, dk);
      }
#pragma unroll
      for (int off = 32; off; off >>= 1) mn = fminf(mn, __shfl_xor(mn, off));
      const float shn = (mn < __builtin_inff()) ? mn : neg_inside;
      losssum += fmaxf(TLMARGIN + dj - shn, 0.0f);
      pcount += 1.0f;
    }

    __syncthreads();  // red[] reuse
    if (lane == 0) { red[wave] = losssum; red[8 + wave] = pcount; }
    __syncthreads();
    if (tid == 0) {
      float ls = 0.0f, pc = 0.0f;
#pragma unroll
      for (int w = 0; w < 8; ++w) { ls += red[w]; pc += red[8 + w]; }
      rl[i] = make_float2(ls, pc);
    }
    __syncthreads();
  }

  // ---- last-block-done global reduction
  if (tid == 0) {
    __threadfence();                       // rl[] visible device-wide
    const unsigned int old = atomicAdd(ticket, 1u);
    lastFlag = (old == NBLOCKS - 1) ? 1 : 0;
  }
  __syncthreads();

  if (lastFlag) {
    __threadfence();
    const volatile float* vr = reinterpret_cast<const volatile float*>(rl);
    float l = vr[2 * tid];
    float c = vr[2 * tid + 1];
#pragma unroll
    for (int off = 32; off; off >>= 1) {
      l += __shfl_xor(l, off);
      c += __shfl_xor(c, off);
    }
    if (lane == 0) { red[wave] = l; red[8 + wave] = c; }
    __syncthreads();
    if (tid == 0) {
      float L = 0.0f, C = 0.0f;
#pragma unroll
      for (int w = 0; w < 8; ++w) { L += red[w]; C += red[8 + w]; }
      out[0] = L / C;
    }
  }
}

extern "C" void kernel_launch(void* const* d_in, const int* in_sizes, int n_in,
                              void* d_out, int out_size, void* d_ws, size_t ws_size,
                              hipStream_t stream) {
  const float* inp = (const float*)d_in[0];
  const int* tgt = (const int*)d_in[1];
  float* out = (float*)d_out;

  char* ws = (char*)d_ws;
  float2* rl = (float2*)ws;                         // 4 KB
  unsigned int* ticket = (unsigned int*)(ws + 4096);

  hipMemsetAsync(ticket, 0, sizeof(unsigned int), stream);
  triplet_all<<<NBLOCKS, 512, 0, stream>>>(inp, tgt, rl, ticket, out);
}

// Round 7
// 27.794 us; speedup vs baseline: 1.0666x; 1.0666x over previous
//
#include <hip/hip_runtime.h>

#define N_PTS 512
#define DIM 128
#define F4_PER_ROW 32
#define NBLOCKS 256
#define TLMARGIN 1.0f

// K1: transpose input (512x128 f32) into Tv[t4][j] (float4), LDS-staged so both
// global read and write are coalesced. Also resets the ticket for K2's tail.
// 8 blocks x 512 threads, 64 rows per block.
__global__ __launch_bounds__(512)
void k_transpose(const float* __restrict__ inp,
                 float4* __restrict__ Tv,
                 unsigned int* __restrict__ ticket) {
  __shared__ float4 lds[64 * 33];
  const int b = blockIdx.x;
  const int tid = threadIdx.x;

  if (b == 0 && tid == 0) *ticket = 0u;  // visible to K2 at kernel boundary

  const float4* inp4 = reinterpret_cast<const float4*>(inp);
#pragma unroll
  for (int q = 0; q < 4; ++q) {
    const int idx = q * 512 + tid;          // 0..2047
    const int row = idx >> 5, col = idx & 31;
    lds[row * 33 + col] = inp4[b * 2048 + idx];   // coalesced read
  }
  __syncthreads();
#pragma unroll
  for (int q = 0; q < 4; ++q) {
    const int idx = q * 512 + tid;
    const int col = idx >> 6, r = idx & 63;
    Tv[col * N_PTS + b * 64 + r] = lds[r * 33 + col];  // 1KB contiguous runs
  }
}

// K2: 256 blocks x 512 threads; block b owns anchors {2b, 2b+1}.
// Phase 1: thread j streams Tv column j (32 coalesced float4 loads, no syncs,
//          no shuffles) computing dot0, dot1 and ||row j||^2 in one pass.
// Phase 2: semi-hard mining (verified round-5 code).
// Phase 3: ticket + last-block reduction (verified round-6 code).
__global__ __launch_bounds__(512)
void k_main(const float* __restrict__ inp,
            const int* __restrict__ tgt,
            const float4* __restrict__ Tv,
            float2* __restrict__ rl,
            unsigned int* __restrict__ ticket,
            float* __restrict__ out) {
  const int i0 = blockIdx.x * 2;
  const int tid = threadIdx.x;
  const int lane = tid & 63;
  const int wave = tid >> 6;

  __shared__ float4 rowa[2][F4_PER_ROW];
  __shared__ float sqs[N_PTS];
  __shared__ float d[2][N_PTS];
  __shared__ int lab[N_PTS];
  __shared__ float red[16];
  __shared__ unsigned long long pmask[8];
  __shared__ int plist[N_PTS];
  __shared__ int lastFlag;

  lab[tid] = tgt[tid];
  if (tid < 64) {
    const int rr = tid >> 5;
    const int t4 = tid & 31;
    rowa[rr][t4] = reinterpret_cast<const float4*>(inp + (i0 + rr) * DIM)[t4];
  }
  __syncthreads();

  // ---- Phase 1: dots + squared norm in one coalesced Tv pass
  float dot0 = 0.0f, dot1 = 0.0f, sj = 0.0f;
#pragma unroll 16
  for (int t4 = 0; t4 < F4_PER_ROW; ++t4) {
    const float4 bv = Tv[t4 * N_PTS + tid];
    const float4 a0 = rowa[0][t4];
    const float4 a1 = rowa[1][t4];
    dot0 += a0.x * bv.x + a0.y * bv.y + a0.z * bv.z + a0.w * bv.w;
    dot1 += a1.x * bv.x + a1.y * bv.y + a1.z * bv.z + a1.w * bv.w;
    sj   += bv.x * bv.x + bv.y * bv.y + bv.z * bv.z + bv.w * bv.w;
  }
  sqs[tid] = sj;
  __syncthreads();

  float pd0 = fmaxf(sqs[i0] + sj - 2.0f * dot0, 0.0f);
  float pd1 = fmaxf(sqs[i0 + 1] + sj - 2.0f * dot1, 0.0f);
  if (tid == i0) pd0 = 0.0f;
  if (tid == i0 + 1) pd1 = 0.0f;
  d[0][tid] = pd0;
  d[1][tid] = pd1;
  __syncthreads();

  // ---- Phase 2: per-row semi-hard mining (verified)
  for (int r = 0; r < 2; ++r) {
    const int i = i0 + r;
    const int li = lab[i];

    float nm = (lab[tid] != li) ? d[r][tid] : 0.0f;
#pragma unroll
    for (int off = 32; off; off >>= 1) nm = fmaxf(nm, __shfl_xor(nm, off));
    if (lane == 0) red[wave] = nm;

    const bool isPos = (lab[tid] == li) && (tid != i);
    const unsigned long long m = __ballot(isPos);
    if (lane == 0) pmask[wave] = m;
    __syncthreads();

    float neg_inside = red[0];
#pragma unroll
    for (int w = 1; w < 8; ++w) neg_inside = fmaxf(neg_inside, red[w]);

    int P = 0, rank = 0;
#pragma unroll
    for (int w = 0; w < 8; ++w) {
      const int c = __popcll(pmask[w]);
      if (w < wave) rank += c;
      P += c;
    }
    rank += __popcll(pmask[wave] & ((1ull << lane) - 1ull));
    if (isPos) plist[rank] = tid;
    __syncthreads();

    float losssum = 0.0f;
    float pcount = 0.0f;
    for (int p = wave; p < P; p += 8) {
      const int j = plist[p];
      const float dj = d[r][j];
      float mn = __builtin_inff();
#pragma unroll
      for (int kk = 0; kk < N_PTS / 64; ++kk) {
        const int k = lane + (kk << 6);
        const float dk = d[r][k];
        if (lab[k] != li && dk > dj) mn = fminf(mn, dk);
      }
#pragma unroll
      for (int off = 32; off; off >>= 1) mn = fminf(mn, __shfl_xor(mn, off));
      const float shn = (mn < __builtin_inff()) ? mn : neg_inside;
      losssum += fmaxf(TLMARGIN + dj - shn, 0.0f);
      pcount += 1.0f;
    }

    __syncthreads();  // red[] reuse
    if (lane == 0) { red[wave] = losssum; red[8 + wave] = pcount; }
    __syncthreads();
    if (tid == 0) {
      float ls = 0.0f, pc = 0.0f;
#pragma unroll
      for (int w = 0; w < 8; ++w) { ls += red[w]; pc += red[8 + w]; }
      rl[i] = make_float2(ls, pc);
    }
    __syncthreads();
  }

  // ---- Phase 3: last-block-done global reduction (verified)
  if (tid == 0) {
    __threadfence();
    const unsigned int old = atomicAdd(ticket, 1u);
    lastFlag = (old == NBLOCKS - 1) ? 1 : 0;
  }
  __syncthreads();

  if (lastFlag) {
    __threadfence();
    const volatile float* vr = reinterpret_cast<const volatile float*>(rl);
    float l = vr[2 * tid];
    float c = vr[2 * tid + 1];
#pragma unroll
    for (int off = 32; off; off >>= 1) {
      l += __shfl_xor(l, off);
      c += __shfl_xor(c, off);
    }
    if (lane == 0) { red[wave] = l; red[8 + wave] = c; }
    __syncthreads();
    if (tid == 0) {
      float L = 0.0f, C = 0.0f;
#pragma unroll
      for (int w = 0; w < 8; ++w) { L += red[w]; C += red[8 + w]; }
      out[0] = L / C;
    }
  }
}

extern "C" void kernel_launch(void* const* d_in, const int* in_sizes, int n_in,
                              void* d_out, int out_size, void* d_ws, size_t ws_size,
                              hipStream_t stream) {
  const float* inp = (const float*)d_in[0];
  const int* tgt = (const int*)d_in[1];
  float* out = (float*)d_out;

  char* ws = (char*)d_ws;
  float4* Tv = (float4*)ws;                             // 256 KB
  float2* rl = (float2*)(ws + 262144);                  // 4 KB
  unsigned int* ticket = (unsigned int*)(ws + 262144 + 4096);

  k_transpose<<<8, 512, 0, stream>>>(inp, Tv, ticket);
  k_main<<<NBLOCKS, 512, 0, stream>>>(inp, tgt, Tv, rl, ticket, out);
}

// Round 8
// 23.427 us; speedup vs baseline: 1.2655x; 1.1864x over previous
//
#include <hip/hip_runtime.h>

#define N_PTS 512
#define DIM 128
#define F4_PER_ROW 32
#define TLMARGIN 1.0f

// K1: transpose input (512x128 f32) -> Tv[t4][j] (float4). LDS-staged:
// coalesced global reads AND writes (512B contiguous runs per 32 lanes).
// 16 blocks x 512 threads, 32 rows per block.
__global__ __launch_bounds__(512)
void k_transpose(const float* __restrict__ inp, float4* __restrict__ Tv) {
  __shared__ float4 lds[32 * 33];
  const int b = blockIdx.x;
  const int tid = threadIdx.x;
  const float4* inp4 = reinterpret_cast<const float4*>(inp);
#pragma unroll
  for (int q = 0; q < 2; ++q) {
    const int idx = q * 512 + tid;            // 0..1023
    const int row = idx >> 5, col = idx & 31;
    lds[row * 33 + col] = inp4[b * 1024 + idx];        // coalesced read
  }
  __syncthreads();
#pragma unroll
  for (int q = 0; q < 2; ++q) {
    const int idx = q * 512 + tid;
    const int col = idx >> 5, r = idx & 31;
    Tv[col * N_PTS + b * 32 + r] = lds[r * 33 + col];  // 512B runs
  }
}

// K2: 256 blocks x 512 threads; block b owns anchors {2b, 2b+1}.
// Phase 1: thread j streams Tv column j (32 coalesced float4 loads, no syncs),
//          computing dot0, dot1, ||row j||^2, ||a0||^2, ||a1||^2 in one pass
//          (anchor norms recomputed per-thread -> no broadcast sync needed).
// Phase 2: semi-hard mining for both rows with 3 syncs total.
__global__ __launch_bounds__(512)
void k_rows(const float* __restrict__ inp,
            const int* __restrict__ tgt,
            const float4* __restrict__ Tv,
            float2* __restrict__ rl) {
  const int i0 = blockIdx.x * 2;
  const int tid = threadIdx.x;
  const int lane = tid & 63;
  const int wave = tid >> 6;

  __shared__ float4 rowa[2][F4_PER_ROW];
  __shared__ float d[2][N_PTS];
  __shared__ int lab[N_PTS];
  __shared__ float red[32];
  __shared__ unsigned long long pm0[8];
  __shared__ unsigned long long pm1[8];
  __shared__ int plist0[N_PTS];
  __shared__ int plist1[N_PTS];

  lab[tid] = tgt[tid];
  if (tid < 64) {
    const int rr = tid >> 5;
    const int t4 = tid & 31;
    rowa[rr][t4] = reinterpret_cast<const float4*>(inp + (i0 + rr) * DIM)[t4];
  }
  __syncthreads();                                    // sync A

  // ---- Phase 1: one pass over Tv column tid
  float dot0 = 0.0f, dot1 = 0.0f, sj = 0.0f, sa0 = 0.0f, sa1 = 0.0f;
#pragma unroll 8
  for (int t4 = 0; t4 < F4_PER_ROW; ++t4) {
    const float4 bv = Tv[t4 * N_PTS + tid];
    const float4 a0 = rowa[0][t4];
    const float4 a1 = rowa[1][t4];
    dot0 += a0.x * bv.x + a0.y * bv.y + a0.z * bv.z + a0.w * bv.w;
    dot1 += a1.x * bv.x + a1.y * bv.y + a1.z * bv.z + a1.w * bv.w;
    sj   += bv.x * bv.x + bv.y * bv.y + bv.z * bv.z + bv.w * bv.w;
    sa0  += a0.x * a0.x + a0.y * a0.y + a0.z * a0.z + a0.w * a0.w;
    sa1  += a1.x * a1.x + a1.y * a1.y + a1.z * a1.z + a1.w * a1.w;
  }
  float pd0 = fmaxf(sa0 + sj - 2.0f * dot0, 0.0f);
  float pd1 = fmaxf(sa1 + sj - 2.0f * dot1, 0.0f);
  if (tid == i0) pd0 = 0.0f;
  if (tid == i0 + 1) pd1 = 0.0f;
  d[0][tid] = pd0;
  d[1][tid] = pd1;

  const int li0 = lab[i0];
  const int li1 = lab[i0 + 1];

  // ---- per-wave max over negatives + positive ballots for BOTH rows
  float nm0 = (lab[tid] != li0) ? pd0 : 0.0f;
  float nm1 = (lab[tid] != li1) ? pd1 : 0.0f;
#pragma unroll
  for (int off = 32; off; off >>= 1) {
    nm0 = fmaxf(nm0, __shfl_xor(nm0, off));
    nm1 = fmaxf(nm1, __shfl_xor(nm1, off));
  }
  const bool isPos0 = (lab[tid] == li0) && (tid != i0);
  const bool isPos1 = (lab[tid] == li1) && (tid != i0 + 1);
  const unsigned long long m0 = __ballot(isPos0);
  const unsigned long long m1 = __ballot(isPos1);
  if (lane == 0) {
    red[wave] = nm0;
    red[8 + wave] = nm1;
    pm0[wave] = m0;
    pm1[wave] = m1;
  }
  __syncthreads();                                    // sync B (publishes d, red, pm)

  float negin0 = red[0], negin1 = red[8];
#pragma unroll
  for (int w = 1; w < 8; ++w) {
    negin0 = fmaxf(negin0, red[w]);
    negin1 = fmaxf(negin1, red[8 + w]);
  }

  int P0 = 0, rank0 = 0, P1 = 0, rank1 = 0;
#pragma unroll
  for (int w = 0; w < 8; ++w) {
    const int c0 = __popcll(pm0[w]);
    const int c1 = __popcll(pm1[w]);
    if (w < wave) { rank0 += c0; rank1 += c1; }
    P0 += c0;
    P1 += c1;
  }
  rank0 += __popcll(pm0[wave] & ((1ull << lane) - 1ull));
  rank1 += __popcll(pm1[wave] & ((1ull << lane) - 1ull));
  if (isPos0) plist0[rank0] = tid;
  if (isPos1) plist1[rank1] = tid;
  __syncthreads();                                    // sync C (publishes plists)

  // ---- mine both rows: wave w takes entries w, w+8, ...
  float ls0 = 0.0f, pc0 = 0.0f, ls1 = 0.0f, pc1 = 0.0f;
  for (int p = wave; p < P0; p += 8) {
    const int j = plist0[p];
    const float dj = d[0][j];
    float mn = __builtin_inff();
#pragma unroll
    for (int kk = 0; kk < N_PTS / 64; ++kk) {
      const int k = lane + (kk << 6);
      const float dk = d[0][k];
      if (lab[k] != li0 && dk > dj) mn = fminf(mn, dk);
    }
#pragma unroll
    for (int off = 32; off; off >>= 1) mn = fminf(mn, __shfl_xor(mn, off));
    const float shn = (mn < __builtin_inff()) ? mn : negin0;
    ls0 += fmaxf(TLMARGIN + dj - shn, 0.0f);
    pc0 += 1.0f;
  }
  for (int p = wave; p < P1; p += 8) {
    const int j = plist1[p];
    const float dj = d[1][j];
    float mn = __builtin_inff();
#pragma unroll
    for (int kk = 0; kk < N_PTS / 64; ++kk) {
      const int k = lane + (kk << 6);
      const float dk = d[1][k];
      if (lab[k] != li1 && dk > dj) mn = fminf(mn, dk);
    }
#pragma unroll
    for (int off = 32; off; off >>= 1) mn = fminf(mn, __shfl_xor(mn, off));
    const float shn = (mn < __builtin_inff()) ? mn : negin1;
    ls1 += fmaxf(TLMARGIN + dj - shn, 0.0f);
    pc1 += 1.0f;
  }

  if (lane == 0) {
    red[wave] = ls0;
    red[8 + wave] = pc0;
    red[16 + wave] = ls1;
    red[24 + wave] = pc1;
  }
  __syncthreads();                                    // sync D
  if (tid == 0) {
    float a = 0.f, b = 0.f, c = 0.f, e = 0.f;
#pragma unroll
    for (int w = 0; w < 8; ++w) {
      a += red[w];
      b += red[8 + w];
      c += red[16 + w];
      e += red[24 + w];
    }
    rl[i0] = make_float2(a, b);
    rl[i0 + 1] = make_float2(c, e);
  }
}

// K3: 1 block x 256 threads -> scalar loss
__global__ __launch_bounds__(256)
void k_reduce(const float2* __restrict__ rl, float* __restrict__ out) {
  __shared__ float red[8];
  const int tid = threadIdx.x;
  const float2 a = rl[tid];
  const float2 b = rl[tid + 256];
  float l = a.x + b.x;
  float c = a.y + b.y;
#pragma unroll
  for (int off = 32; off; off >>= 1) {
    l += __shfl_xor(l, off);
    c += __shfl_xor(c, off);
  }
  const int lane = tid & 63, wave = tid >> 6;
  if (lane == 0) { red[wave] = l; red[4 + wave] = c; }
  __syncthreads();
  if (tid == 0) {
    float L = 0.0f, C = 0.0f;
#pragma unroll
    for (int w = 0; w < 4; ++w) { L += red[w]; C += red[4 + w]; }
    out[0] = L / C;
  }
}

extern "C" void kernel_launch(void* const* d_in, const int* in_sizes, int n_in,
                              void* d_out, int out_size, void* d_ws, size_t ws_size,
                              hipStream_t stream) {
  const float* inp = (const float*)d_in[0];
  const int* tgt = (const int*)d_in[1];
  float* out = (float*)d_out;

  char* ws = (char*)d_ws;
  float4* Tv = (float4*)ws;               // 256 KB
  float2* rl = (float2*)(ws + 262144);    // 4 KB

  k_transpose<<<16, 512, 0, stream>>>(inp, Tv);
  k_rows<<<N_PTS / 2, 512, 0, stream>>>(inp, tgt, Tv, rl);
  k_reduce<<<1, 256, 0, stream>>>(rl, out);
}

// Round 9
// 16.003 us; speedup vs baseline: 1.8525x; 1.4639x over previous
//
#include <hip/hip_runtime.h>

#define N_PTS 512
#define DIM 128
#define F4_PER_ROW 32
#define TLMARGIN 1.0f

// K1: 256 blocks x 512 threads; block b owns anchors {2b, 2b+1}.
// Phase 1: 8-lane cooperative dots DIRECTLY from row-major input:
//   lane s of group G takes float4 slice {q*8+s}; per instruction a wave reads
//   8 consecutive rows x 128B = 1KB contiguous. 3-level __shfl_xor reduce.
//   No transpose kernel, no LDS staging, no pre-sync.
// Phase 2: semi-hard mining for both rows (verified round-8 code).
__global__ __launch_bounds__(512)
void k_rows(const float* __restrict__ inp,
            const int* __restrict__ tgt,
            float2* __restrict__ rl) {
  const int i0 = blockIdx.x * 2;
  const int tid = threadIdx.x;
  const int lane = tid & 63;
  const int wave = tid >> 6;
  const int G = tid >> 3;   // 8-lane group id (0..63)
  const int s = tid & 7;    // lane within group

  __shared__ float d[2][N_PTS];
  __shared__ int lab[N_PTS];
  __shared__ float red[32];
  __shared__ unsigned long long pm0[8];
  __shared__ unsigned long long pm1[8];
  __shared__ int plist0[N_PTS];
  __shared__ int plist1[N_PTS];

  lab[tid] = tgt[tid];

  const float4* inp4 = reinterpret_cast<const float4*>(inp);

  // ---- anchor slice fragments (4 float4 per anchor per lane) + norms
  float4 a0f[4], a1f[4];
  float sa0 = 0.f, sa1 = 0.f;
#pragma unroll
  for (int q = 0; q < 4; ++q) {
    a0f[q] = inp4[i0 * F4_PER_ROW + q * 8 + s];
    a1f[q] = inp4[(i0 + 1) * F4_PER_ROW + q * 8 + s];
    sa0 += a0f[q].x * a0f[q].x + a0f[q].y * a0f[q].y + a0f[q].z * a0f[q].z + a0f[q].w * a0f[q].w;
    sa1 += a1f[q].x * a1f[q].x + a1f[q].y * a1f[q].y + a1f[q].z * a1f[q].z + a1f[q].w * a1f[q].w;
  }
#pragma unroll
  for (int off = 1; off <= 4; off <<= 1) {
    sa0 += __shfl_xor(sa0, off);
    sa1 += __shfl_xor(sa1, off);
  }

  // ---- pdist rows: group G handles j = r*64 + G, r = 0..7
#pragma unroll 2
  for (int r = 0; r < 8; ++r) {
    const int j = r * 64 + G;
    float dot0 = 0.f, dot1 = 0.f, sj = 0.f;
#pragma unroll
    for (int q = 0; q < 4; ++q) {
      const float4 bv = inp4[j * F4_PER_ROW + q * 8 + s];  // 1KB/instr per wave
      dot0 += a0f[q].x * bv.x + a0f[q].y * bv.y + a0f[q].z * bv.z + a0f[q].w * bv.w;
      dot1 += a1f[q].x * bv.x + a1f[q].y * bv.y + a1f[q].z * bv.z + a1f[q].w * bv.w;
      sj   += bv.x * bv.x + bv.y * bv.y + bv.z * bv.z + bv.w * bv.w;
    }
#pragma unroll
    for (int off = 1; off <= 4; off <<= 1) {
      dot0 += __shfl_xor(dot0, off);
      dot1 += __shfl_xor(dot1, off);
      sj   += __shfl_xor(sj, off);
    }
    if (s == 0) {
      float pd0 = fmaxf(sa0 + sj - 2.0f * dot0, 0.0f);
      float pd1 = fmaxf(sa1 + sj - 2.0f * dot1, 0.0f);
      if (j == i0) pd0 = 0.0f;
      if (j == i0 + 1) pd1 = 0.0f;
      d[0][j] = pd0;
      d[1][j] = pd1;
    }
  }
  __syncthreads();                                    // publish d + lab

  const int li0 = lab[i0];
  const int li1 = lab[i0 + 1];

  // ---- per-wave max over negatives + positive ballots for BOTH rows
  const float d0t = d[0][tid];
  const float d1t = d[1][tid];
  float nm0 = (lab[tid] != li0) ? d0t : 0.0f;
  float nm1 = (lab[tid] != li1) ? d1t : 0.0f;
#pragma unroll
  for (int off = 32; off; off >>= 1) {
    nm0 = fmaxf(nm0, __shfl_xor(nm0, off));
    nm1 = fmaxf(nm1, __shfl_xor(nm1, off));
  }
  const bool isPos0 = (lab[tid] == li0) && (tid != i0);
  const bool isPos1 = (lab[tid] == li1) && (tid != i0 + 1);
  const unsigned long long m0 = __ballot(isPos0);
  const unsigned long long m1 = __ballot(isPos1);
  if (lane == 0) {
    red[wave] = nm0;
    red[8 + wave] = nm1;
    pm0[wave] = m0;
    pm1[wave] = m1;
  }
  __syncthreads();                                    // publish red, pm

  float negin0 = red[0], negin1 = red[8];
#pragma unroll
  for (int w = 1; w < 8; ++w) {
    negin0 = fmaxf(negin0, red[w]);
    negin1 = fmaxf(negin1, red[8 + w]);
  }

  int P0 = 0, rank0 = 0, P1 = 0, rank1 = 0;
#pragma unroll
  for (int w = 0; w < 8; ++w) {
    const int c0 = __popcll(pm0[w]);
    const int c1 = __popcll(pm1[w]);
    if (w < wave) { rank0 += c0; rank1 += c1; }
    P0 += c0;
    P1 += c1;
  }
  rank0 += __popcll(pm0[wave] & ((1ull << lane) - 1ull));
  rank1 += __popcll(pm1[wave] & ((1ull << lane) - 1ull));
  if (isPos0) plist0[rank0] = tid;
  if (isPos1) plist1[rank1] = tid;
  __syncthreads();                                    // publish plists

  // ---- mine both rows: wave w takes entries w, w+8, ...
  float ls0 = 0.0f, pc0 = 0.0f, ls1 = 0.0f, pc1 = 0.0f;
  for (int p = wave; p < P0; p += 8) {
    const int j = plist0[p];
    const float dj = d[0][j];
    float mn = __builtin_inff();
#pragma unroll
    for (int kk = 0; kk < N_PTS / 64; ++kk) {
      const int k = lane + (kk << 6);
      const float dk = d[0][k];
      if (lab[k] != li0 && dk > dj) mn = fminf(mn, dk);
    }
#pragma unroll
    for (int off = 32; off; off >>= 1) mn = fminf(mn, __shfl_xor(mn, off));
    const float shn = (mn < __builtin_inff()) ? mn : negin0;
    ls0 += fmaxf(TLMARGIN + dj - shn, 0.0f);
    pc0 += 1.0f;
  }
  for (int p = wave; p < P1; p += 8) {
    const int j = plist1[p];
    const float dj = d[1][j];
    float mn = __builtin_inff();
#pragma unroll
    for (int kk = 0; kk < N_PTS / 64; ++kk) {
      const int k = lane + (kk << 6);
      const float dk = d[1][k];
      if (lab[k] != li1 && dk > dj) mn = fminf(mn, dk);
    }
#pragma unroll
    for (int off = 32; off; off >>= 1) mn = fminf(mn, __shfl_xor(mn, off));
    const float shn = (mn < __builtin_inff()) ? mn : negin1;
    ls1 += fmaxf(TLMARGIN + dj - shn, 0.0f);
    pc1 += 1.0f;
  }

  if (lane == 0) {
    red[wave] = ls0;
    red[8 + wave] = pc0;
    red[16 + wave] = ls1;
    red[24 + wave] = pc1;
  }
  __syncthreads();
  if (tid == 0) {
    float a = 0.f, b = 0.f, c = 0.f, e = 0.f;
#pragma unroll
    for (int w = 0; w < 8; ++w) {
      a += red[w];
      b += red[8 + w];
      c += red[16 + w];
      e += red[24 + w];
    }
    rl[i0] = make_float2(a, b);
    rl[i0 + 1] = make_float2(c, e);
  }
}

// K2: 1 block x 256 threads -> scalar loss
__global__ __launch_bounds__(256)
void k_reduce(const float2* __restrict__ rl, float* __restrict__ out) {
  __shared__ float red[8];
  const int tid = threadIdx.x;
  const float2 a = rl[tid];
  const float2 b = rl[tid + 256];
  float l = a.x + b.x;
  float c = a.y + b.y;
#pragma unroll
  for (int off = 32; off; off >>= 1) {
    l += __shfl_xor(l, off);
    c += __shfl_xor(c, off);
  }
  const int lane = tid & 63, wave = tid >> 6;
  if (lane == 0) { red[wave] = l; red[4 + wave] = c; }
  __syncthreads();
  if (tid == 0) {
    float L = 0.0f, C = 0.0f;
#pragma unroll
    for (int w = 0; w < 4; ++w) { L += red[w]; C += red[4 + w]; }
    out[0] = L / C;
  }
}

extern "C" void kernel_launch(void* const* d_in, const int* in_sizes, int n_in,
                              void* d_out, int out_size, void* d_ws, size_t ws_size,
                              hipStream_t stream) {
  const float* inp = (const float*)d_in[0];
  const int* tgt = (const int*)d_in[1];
  float* out = (float*)d_out;

  float2* rl = (float2*)d_ws;   // 4 KB

  k_rows<<<N_PTS / 2, 512, 0, stream>>>(inp, tgt, rl);
  k_reduce<<<1, 256, 0, stream>>>(rl, out);
}